// Round 1
// baseline (1209.832 us; speedup 1.0000x reference)
//
#include <hip/hip_runtime.h>

// ---------------------------------------------------------------------------
// GAT_L3: 3x (GATConv -> BatchNorm -> ReLU) on N=50000 nodes, E=800000 edges
// (+N self-loops). fp32 end-to-end. Layer dims: 128->[2x32] -> 64->[2x32]
// -> 64->[1x32]. GAT bias cancels under training-mode BN (mean-subtracted),
// so it is skipped. BN+ReLU of layer L is fused into layer L+1's GEMM load.
// ---------------------------------------------------------------------------

__device__ __forceinline__ unsigned fenc(float f) {
    unsigned u = __float_as_uint(f);
    return (u & 0x80000000u) ? ~u : (u | 0x80000000u);
}
__device__ __forceinline__ float fdec(unsigned k) {
    return (k & 0x80000000u) ? __uint_as_float(k & 0x7FFFFFFFu)
                             : __uint_as_float(~k);
}
__device__ __forceinline__ float lrelu(float x) { return x > 0.f ? x : 0.2f * x; }

// ---------------------------------------------------------------------------
// GEMM: h[n, j] = sum_k in[n,k] * W[k,j], j in [0,OUTF). 8 nodes per thread
// (register blocking) so the coalesced W column load is reused 8x.
// FUSE: in-value goes through BN scale/shift + ReLU first (prev layer's BN).
// ---------------------------------------------------------------------------
template <int K, int OUTF, bool FUSE>
__global__ __launch_bounds__(256) void gemm_k(
    const float* __restrict__ in, const float* __restrict__ W,
    const float* __restrict__ scale, const float* __restrict__ shift,
    float* __restrict__ h, int N)
{
    constexpr int NPG = 8;  // nodes per thread-group
    int t = blockIdx.x * 256 + threadIdx.x;
    int grp = t / OUTF;
    int j = t - grp * OUTF;
    int n0 = grp * NPG;
    if (n0 >= N) return;

    const float* rows[NPG];
#pragma unroll
    for (int i = 0; i < NPG; ++i) {
        int n = n0 + i;
        if (n >= N) n = N - 1;
        rows[i] = in + (size_t)n * K;
    }
    float acc[NPG];
#pragma unroll
    for (int i = 0; i < NPG; ++i) acc[i] = 0.f;

#pragma unroll 4
    for (int k = 0; k < K; ++k) {
        float w = W[k * OUTF + j];
        float sc = 0.f, sh = 0.f;
        if constexpr (FUSE) { sc = scale[k]; sh = shift[k]; }
#pragma unroll
        for (int i = 0; i < NPG; ++i) {
            float v = rows[i][k];
            if constexpr (FUSE) v = fmaxf(v * sc + sh, 0.f);
            acc[i] += v * w;
        }
    }
#pragma unroll
    for (int i = 0; i < NPG; ++i) {
        int n = n0 + i;
        if (n < N) h[(size_t)n * OUTF + j] = acc[i];
    }
}

// ---------------------------------------------------------------------------
// Per-node attention coefficients: es[n,h] = sum_d h[n,h,d]*a_src[h,d] (same
// for ed). One lane per (node, feature); 32-wide shuffle reduction per head.
// a_src is flat [h*32+d] which matches j exactly.
// ---------------------------------------------------------------------------
template <int OUTF, int H>
__global__ __launch_bounds__(256) void attn_k(
    const float* __restrict__ h, const float* __restrict__ a_src,
    const float* __restrict__ a_dst, float* __restrict__ es,
    float* __restrict__ ed, int N)
{
    int t = blockIdx.x * 256 + threadIdx.x;
    int node = t / OUTF;
    int j = t - node * OUTF;
    if (node >= N) return;
    float v = h[(size_t)node * OUTF + j];
    float p = v * a_src[j];
    float q = v * a_dst[j];
#pragma unroll
    for (int m = 16; m; m >>= 1) {
        p += __shfl_xor(p, m, 32);
        q += __shfl_xor(q, m, 32);
    }
    if ((j & 31) == 0) {
        int head = j >> 5;
        es[node * H + head] = p;
        ed[node * H + head] = q;
    }
}

// ---------------------------------------------------------------------------
// Edge pass A: segment max of leaky-relu logits via ordered-uint atomicMax.
// emax buffer zero-initialized; 0 < fenc(x) for all finite x, and every node
// has a self-loop, so every segment gets at least one real update.
// ---------------------------------------------------------------------------
template <int H>
__global__ __launch_bounds__(256) void edge_max_k(
    const int* __restrict__ ei, const float* __restrict__ es,
    const float* __restrict__ ed, unsigned* __restrict__ emax, int E, int N)
{
    int e = blockIdx.x * 256 + threadIdx.x;
    int Et = E + N;
    if (e >= Et) return;
    int s, d;
    if (e < E) { s = ei[e]; d = ei[E + e]; } else { s = e - E; d = s; }
#pragma unroll
    for (int hh = 0; hh < H; ++hh) {
        float l = lrelu(es[s * H + hh] + ed[d * H + hh]);
        atomicMax(&emax[d * H + hh], fenc(l));
    }
}

// Edge pass B: denom[dst,h] += exp(l - emax[dst,h])
template <int H>
__global__ __launch_bounds__(256) void edge_sum_k(
    const int* __restrict__ ei, const float* __restrict__ es,
    const float* __restrict__ ed, const unsigned* __restrict__ emax,
    float* __restrict__ den, int E, int N)
{
    int e = blockIdx.x * 256 + threadIdx.x;
    int Et = E + N;
    if (e >= Et) return;
    int s, d;
    if (e < E) { s = ei[e]; d = ei[E + e]; } else { s = e - E; d = s; }
#pragma unroll
    for (int hh = 0; hh < H; ++hh) {
        float l = lrelu(es[s * H + hh] + ed[d * H + hh]);
        float ex = expf(l - fdec(emax[d * H + hh]));
        atomicAdd(&den[d * H + hh], ex);
    }
}

// ---------------------------------------------------------------------------
// Edge pass C: agg[dst, f] += alpha(e, head(f)) * h[src, f]. One lane per
// (edge, feature); alpha recomputed per lane (cheap, scalar loads broadcast
// within the 32-lane head group). F = H*32.
// ---------------------------------------------------------------------------
template <int H, int F>
__global__ __launch_bounds__(256) void edge_agg_k(
    const int* __restrict__ ei, const float* __restrict__ es,
    const float* __restrict__ ed, const unsigned* __restrict__ emax,
    const float* __restrict__ den, const float* __restrict__ h,
    float* __restrict__ agg, int E, int N)
{
    int idx = blockIdx.x * 256 + threadIdx.x;
    int e = idx / F;
    int f = idx - e * F;
    int Et = E + N;
    if (e >= Et) return;
    int s, d;
    if (e < E) { s = ei[e]; d = ei[E + e]; } else { s = e - E; d = s; }
    int head = f >> 5;
    float l = lrelu(es[s * H + head] + ed[d * H + head]);
    float ex = expf(l - fdec(emax[d * H + head]));
    float alpha = ex / (den[d * H + head] + 1e-16f);
    atomicAdd(&agg[d * F + f], alpha * h[(size_t)s * F + f]);
}

// ---------------------------------------------------------------------------
// BN stats: per-feature sum / sumsq over the node dimension. Block-level
// partials in LDS, one atomicAdd per (block, feature).
// ---------------------------------------------------------------------------
template <int F>
__global__ __launch_bounds__(256) void bn_stats_k(
    const float* __restrict__ x, float* __restrict__ gsum,
    float* __restrict__ gsumsq, int N)
{
    constexpr int RG = 256 / F;
    int f = threadIdx.x & (F - 1);
    int r = threadIdx.x / F;
    float s = 0.f, s2 = 0.f;
    for (int n = blockIdx.x * RG + r; n < N; n += gridDim.x * RG) {
        float v = x[(size_t)n * F + f];
        s += v;
        s2 += v * v;
    }
    __shared__ float ls[256], ls2[256];
    ls[threadIdx.x] = s;
    ls2[threadIdx.x] = s2;
    __syncthreads();
    if (threadIdx.x < F) {
#pragma unroll
        for (int g = 1; g < RG; ++g) { s += ls[g * F + f]; s2 += ls2[g * F + f]; }
        atomicAdd(&gsum[f], s);
        atomicAdd(&gsumsq[f], s2);
    }
}

// BN finalize: scale/shift such that y = x*scale + shift == (x-mu)*rs*g + be
__global__ void bn_final_k(const float* __restrict__ gsum,
                           const float* __restrict__ gsumsq,
                           const float* __restrict__ gamma,
                           const float* __restrict__ beta,
                           float* __restrict__ scale, float* __restrict__ shift,
                           int N, int F)
{
    int f = threadIdx.x;
    if (f >= F) return;
    float inv = 1.f / (float)N;
    float mu = gsum[f] * inv;
    float var = gsumsq[f] * inv - mu * mu;
    var = fmaxf(var, 0.f);
    float rs = rsqrtf(var + 1e-5f);
    float sc = rs * gamma[f];
    scale[f] = sc;
    shift[f] = beta[f] - mu * sc;
}

// Final epilogue for layer 3: BN + ReLU -> d_out
__global__ __launch_bounds__(256) void out_final_k(
    const float* __restrict__ x, const float* __restrict__ scale,
    const float* __restrict__ shift, float* __restrict__ out, int total)
{
    int i = blockIdx.x * 256 + threadIdx.x;
    if (i >= total) return;
    int f = i & 31;
    out[i] = fmaxf(x[i] * scale[f] + shift[f], 0.f);
}

// ---------------------------------------------------------------------------

extern "C" void kernel_launch(void* const* d_in, const int* in_sizes, int n_in,
                              void* d_out, int out_size, void* d_ws,
                              size_t ws_size, hipStream_t stream)
{
    const float* x   = (const float*)d_in[0];
    const float* W1  = (const float*)d_in[1];
    const float* as1 = (const float*)d_in[2];
    const float* ad1 = (const float*)d_in[3];
    // d_in[4] = b1: cancels under BN (mean-subtracted) -> skipped
    const float* g1  = (const float*)d_in[5];
    const float* be1 = (const float*)d_in[6];
    const float* W2  = (const float*)d_in[7];
    const float* as2 = (const float*)d_in[8];
    const float* ad2 = (const float*)d_in[9];
    const float* g2  = (const float*)d_in[11];
    const float* be2 = (const float*)d_in[12];
    const float* W3  = (const float*)d_in[13];
    const float* as3 = (const float*)d_in[14];
    const float* ad3 = (const float*)d_in[15];
    const float* g3  = (const float*)d_in[17];
    const float* be3 = (const float*)d_in[18];
    const int*   ei  = (const int*)d_in[19];

    const int N = in_sizes[0] / 128;   // 50000
    const int E = in_sizes[19] / 2;    // 800000
    const int Et = E + N;

    // Workspace layout (floats). Zero-region [AGG .. GS2] is contiguous so a
    // single hipMemsetAsync per layer clears agg/denom/emax/bn-partials.
    float* ws = (float*)d_ws;
    size_t off = 0;
    float*    Hb   = ws + off;              off += (size_t)N * 64;
    size_t    aggOff = off;
    float*    AGG  = ws + off;              off += (size_t)N * 64;
    float*    DEN  = ws + off;              off += (size_t)N * 2;
    unsigned* EMAX = (unsigned*)(ws + off); off += (size_t)N * 2;
    float*    GS   = ws + off;              off += 64;
    float*    GS2  = ws + off;              off += 64;
    size_t    zeroEnd = off;
    float*    ES   = ws + off;              off += (size_t)N * 2;
    float*    ED   = ws + off;              off += (size_t)N * 2;
    float*    SC   = ws + off;              off += 64;
    float*    SH   = ws + off;              off += 64;
    const size_t zeroBytes = (zeroEnd - aggOff) * sizeof(float);

    const int gemmBlocks64 = (((N + 7) / 8) * 64 + 255) / 256;
    const int gemmBlocks32 = (((N + 7) / 8) * 32 + 255) / 256;
    const int attnBlocks64 = (N * 64 + 255) / 256;
    const int attnBlocks32 = (N * 32 + 255) / 256;
    const int edgeBlocks   = (Et + 255) / 256;
    const int aggBlocks64  = (int)(((size_t)Et * 64 + 255) / 256);
    const int aggBlocks32  = (int)(((size_t)Et * 32 + 255) / 256);

    // ---------------- Layer 1: 128 -> [2 x 32] ----------------
    gemm_k<128, 64, false><<<gemmBlocks64, 256, 0, stream>>>(x, W1, nullptr, nullptr, Hb, N);
    attn_k<64, 2><<<attnBlocks64, 256, 0, stream>>>(Hb, as1, ad1, ES, ED, N);
    hipMemsetAsync(AGG, 0, zeroBytes, stream);
    edge_max_k<2><<<edgeBlocks, 256, 0, stream>>>(ei, ES, ED, EMAX, E, N);
    edge_sum_k<2><<<edgeBlocks, 256, 0, stream>>>(ei, ES, ED, EMAX, DEN, E, N);
    edge_agg_k<2, 64><<<aggBlocks64, 256, 0, stream>>>(ei, ES, ED, EMAX, DEN, Hb, AGG, E, N);
    bn_stats_k<64><<<256, 256, 0, stream>>>(AGG, GS, GS2, N);
    bn_final_k<<<1, 64, 0, stream>>>(GS, GS2, g1, be1, SC, SH, N, 64);

    // ---------------- Layer 2: 64 -> [2 x 32] ----------------
    gemm_k<64, 64, true><<<gemmBlocks64, 256, 0, stream>>>(AGG, W2, SC, SH, Hb, N);
    attn_k<64, 2><<<attnBlocks64, 256, 0, stream>>>(Hb, as2, ad2, ES, ED, N);
    hipMemsetAsync(AGG, 0, zeroBytes, stream);
    edge_max_k<2><<<edgeBlocks, 256, 0, stream>>>(ei, ES, ED, EMAX, E, N);
    edge_sum_k<2><<<edgeBlocks, 256, 0, stream>>>(ei, ES, ED, EMAX, DEN, E, N);
    edge_agg_k<2, 64><<<aggBlocks64, 256, 0, stream>>>(ei, ES, ED, EMAX, DEN, Hb, AGG, E, N);
    bn_stats_k<64><<<256, 256, 0, stream>>>(AGG, GS, GS2, N);
    bn_final_k<<<1, 64, 0, stream>>>(GS, GS2, g2, be2, SC, SH, N, 64);

    // ---------------- Layer 3: 64 -> [1 x 32] ----------------
    gemm_k<64, 32, true><<<gemmBlocks32, 256, 0, stream>>>(AGG, W3, SC, SH, Hb, N);
    attn_k<32, 1><<<attnBlocks32, 256, 0, stream>>>(Hb, as3, ad3, ES, ED, N);
    hipMemsetAsync(AGG, 0, zeroBytes, stream);
    edge_max_k<1><<<edgeBlocks, 256, 0, stream>>>(ei, ES, ED, EMAX, E, N);
    edge_sum_k<1><<<edgeBlocks, 256, 0, stream>>>(ei, ES, ED, EMAX, DEN, E, N);
    edge_agg_k<1, 32><<<aggBlocks32, 256, 0, stream>>>(ei, ES, ED, EMAX, DEN, Hb, AGG, E, N);
    bn_stats_k<32><<<256, 256, 0, stream>>>(AGG, GS, GS2, N);
    bn_final_k<<<1, 32, 0, stream>>>(GS, GS2, g3, be3, SC, SH, N, 32);
    out_final_k<<<attnBlocks32, 256, 0, stream>>>(AGG, SC, SH, (float*)d_out, N * 32);
}

// Round 2
// 661.086 us; speedup vs baseline: 1.8301x; 1.8301x over previous
//
#include <hip/hip_runtime.h>

// ---------------------------------------------------------------------------
// GAT_L3: 3x (GATConv -> BatchNorm -> ReLU), N=50000, E=800000 (+N self-loops).
// Round 2: CSR (dst-sorted) built once per call; per-node gather aggregation
// with wave reductions replaces all float atomics (round-1 edge_agg_k was
// write-through-atomic bound: 212 MB WRITE_SIZE, 23% HBM, 192 us/dispatch).
// ---------------------------------------------------------------------------

__device__ __forceinline__ float lrelu(float x) { return x > 0.f ? x : 0.2f * x; }

// ---------------------------------------------------------------------------
// GEMM: h[n, j] = sum_k in[n,k] * W[k,j]. 8 nodes/thread register blocking.
// FUSE: apply previous layer's BN scale/shift + ReLU to the input value.
// ---------------------------------------------------------------------------
template <int K, int OUTF, bool FUSE>
__global__ __launch_bounds__(256) void gemm_k(
    const float* __restrict__ in, const float* __restrict__ W,
    const float* __restrict__ scale, const float* __restrict__ shift,
    float* __restrict__ h, int N)
{
    constexpr int NPG = 8;
    int t = blockIdx.x * 256 + threadIdx.x;
    int grp = t / OUTF;
    int j = t - grp * OUTF;
    int n0 = grp * NPG;
    if (n0 >= N) return;

    const float* rows[NPG];
#pragma unroll
    for (int i = 0; i < NPG; ++i) {
        int n = n0 + i;
        if (n >= N) n = N - 1;
        rows[i] = in + (size_t)n * K;
    }
    float acc[NPG];
#pragma unroll
    for (int i = 0; i < NPG; ++i) acc[i] = 0.f;

#pragma unroll 4
    for (int k = 0; k < K; ++k) {
        float w = W[k * OUTF + j];
        float sc = 0.f, sh = 0.f;
        if constexpr (FUSE) { sc = scale[k]; sh = shift[k]; }
#pragma unroll
        for (int i = 0; i < NPG; ++i) {
            float v = rows[i][k];
            if constexpr (FUSE) v = fmaxf(v * sc + sh, 0.f);
            acc[i] += v * w;
        }
    }
#pragma unroll
    for (int i = 0; i < NPG; ++i) {
        int n = n0 + i;
        if (n < N) h[(size_t)n * OUTF + j] = acc[i];
    }
}

// ---------------------------------------------------------------------------
// Per-node attention coefficients via 32-wide shuffle reduction.
// ---------------------------------------------------------------------------
template <int OUTF, int H>
__global__ __launch_bounds__(256) void attn_k(
    const float* __restrict__ h, const float* __restrict__ a_src,
    const float* __restrict__ a_dst, float* __restrict__ es,
    float* __restrict__ ed, int N)
{
    int t = blockIdx.x * 256 + threadIdx.x;
    int node = t / OUTF;
    int j = t - node * OUTF;
    if (node >= N) return;
    float v = h[(size_t)node * OUTF + j];
    float p = v * a_src[j];
    float q = v * a_dst[j];
#pragma unroll
    for (int m = 16; m; m >>= 1) {
        p += __shfl_xor(p, m, 32);
        q += __shfl_xor(q, m, 32);
    }
    if ((j & 31) == 0) {
        int head = j >> 5;
        es[node * H + head] = p;
        ed[node * H + head] = q;
    }
}

// ---------------------------------------------------------------------------
// CSR build: degree histogram -> two-level exclusive scan -> scatter.
// Self-loop edge e in [E, E+N) has src = dst = e - E.
// ---------------------------------------------------------------------------
__global__ __launch_bounds__(256) void deg_k(
    const int* __restrict__ ei, int* __restrict__ deg, int E, int N)
{
    int e = blockIdx.x * 256 + threadIdx.x;
    int Et = E + N;
    if (e >= Et) return;
    int d = (e < E) ? ei[E + e] : e - E;
    atomicAdd(&deg[d], 1);
}

// per-block exclusive scan; block totals to bsum
__global__ __launch_bounds__(256) void scan1_k(
    const int* __restrict__ deg, int* __restrict__ rowtmp,
    int* __restrict__ bsum, int N)
{
    __shared__ int ls[256];
    int i = blockIdx.x * 256 + threadIdx.x;
    int v = (i < N) ? deg[i] : 0;
    int x = v;
    ls[threadIdx.x] = x;
    __syncthreads();
#pragma unroll
    for (int ofs = 1; ofs < 256; ofs <<= 1) {
        int y = (threadIdx.x >= ofs) ? ls[threadIdx.x - ofs] : 0;
        __syncthreads();
        x += y;
        ls[threadIdx.x] = x;
        __syncthreads();
    }
    if (i < N) rowtmp[i] = x - v;               // exclusive
    if (threadIdx.x == 255) bsum[blockIdx.x] = x;  // block total
}

// single-block exclusive scan of block sums (nb <= 256)
__global__ __launch_bounds__(256) void scan2_k(
    const int* __restrict__ bsum, int* __restrict__ boff, int nb)
{
    __shared__ int ls[256];
    int i = threadIdx.x;
    int v = (i < nb) ? bsum[i] : 0;
    int x = v;
    ls[i] = x;
    __syncthreads();
#pragma unroll
    for (int ofs = 1; ofs < 256; ofs <<= 1) {
        int y = (i >= ofs) ? ls[i - ofs] : 0;
        __syncthreads();
        x += y;
        ls[i] = x;
        __syncthreads();
    }
    if (i < nb) boff[i] = x - v;
}

__global__ __launch_bounds__(256) void scan3_k(
    const int* __restrict__ rowtmp, const int* __restrict__ boff,
    int* __restrict__ rowptr, int N, int Et)
{
    int i = blockIdx.x * 256 + threadIdx.x;
    if (i < N) rowptr[i] = rowtmp[i] + boff[blockIdx.x];
    if (i == 0) rowptr[N] = Et;
}

__global__ __launch_bounds__(256) void scatter_k(
    const int* __restrict__ ei, const int* __restrict__ rowptr,
    int* __restrict__ cur, int* __restrict__ col, int E, int N)
{
    int e = blockIdx.x * 256 + threadIdx.x;
    int Et = E + N;
    if (e >= Et) return;
    int s, d;
    if (e < E) { s = ei[e]; d = ei[E + e]; } else { s = e - E; d = s; }
    int pos = atomicAdd(&cur[d], 1);
    col[rowptr[d] + pos] = s;
}

// ---------------------------------------------------------------------------
// Per-node softmax-gather aggregation. F = H*32 lanes per node (aligned
// subgroup of a wave). Phase 1: per-head max then exp-sum over in-edges
// (edges strided across the F lanes, butterfly reductions). Phase 2: all
// lanes walk every edge; lane f accumulates alpha_e * h[src_e, f] with the
// 256B h-row load coalesced across the group. No atomics; coalesced output.
// ---------------------------------------------------------------------------
template <int H>
__global__ __launch_bounds__(256) void node_agg_k(
    const int* __restrict__ rowptr, const int* __restrict__ col,
    const float* __restrict__ es, const float* __restrict__ ed,
    const float* __restrict__ h, float* __restrict__ out, int N)
{
    constexpr int F = H * 32;
    int t = blockIdx.x * 256 + threadIdx.x;
    int node = t / F;
    int lane = t - node * F;
    if (node >= N) return;
    int base = rowptr[node];
    int deg = rowptr[node + 1] - base;

    float ed0 = ed[node * H + 0];
    float ed1 = (H == 2) ? ed[node * H + 1] : 0.f;

    // phase 1a: per-head max
    float mx0 = -1e30f, mx1 = -1e30f;
    for (int e = lane; e < deg; e += F) {
        int s = col[base + e];
        mx0 = fmaxf(mx0, lrelu(es[s * H + 0] + ed0));
        if (H == 2) mx1 = fmaxf(mx1, lrelu(es[s * H + 1] + ed1));
    }
#pragma unroll
    for (int m = F / 2; m; m >>= 1) {
        mx0 = fmaxf(mx0, __shfl_xor(mx0, m));
        if (H == 2) mx1 = fmaxf(mx1, __shfl_xor(mx1, m));
    }
    // phase 1b: exp-sum
    float s0 = 0.f, s1 = 0.f;
    for (int e = lane; e < deg; e += F) {
        int s = col[base + e];
        s0 += __expf(lrelu(es[s * H + 0] + ed0) - mx0);
        if (H == 2) s1 += __expf(lrelu(es[s * H + 1] + ed1) - mx1);
    }
#pragma unroll
    for (int m = F / 2; m; m >>= 1) {
        s0 += __shfl_xor(s0, m);
        if (H == 2) s1 += __shfl_xor(s1, m);
    }
    float rd0 = 1.f / (s0 + 1e-16f);
    float rd1 = (H == 2) ? 1.f / (s1 + 1e-16f) : 0.f;

    int head = lane >> 5;                       // 0 for H==1
    float mxh = (H == 2 && head) ? mx1 : mx0;
    float rdh = (H == 2 && head) ? rd1 : rd0;
    float edh = (H == 2 && head) ? ed1 : ed0;

    // phase 2: weighted gather
    float acc = 0.f;
    for (int e = 0; e < deg; ++e) {
        int s = col[base + e];
        float l = lrelu(es[s * H + head] + edh);
        float alpha = __expf(l - mxh) * rdh;
        acc += alpha * h[(size_t)s * F + lane];
    }
    out[(size_t)node * F + lane] = acc;
}

// ---------------------------------------------------------------------------
// BN stats + finalize (scale/shift form so BN+ReLU fuses into next GEMM).
// ---------------------------------------------------------------------------
template <int F>
__global__ __launch_bounds__(256) void bn_stats_k(
    const float* __restrict__ x, float* __restrict__ gsum,
    float* __restrict__ gsumsq, int N)
{
    constexpr int RG = 256 / F;
    int f = threadIdx.x & (F - 1);
    int r = threadIdx.x / F;
    float s = 0.f, s2 = 0.f;
    for (int n = blockIdx.x * RG + r; n < N; n += gridDim.x * RG) {
        float v = x[(size_t)n * F + f];
        s += v;
        s2 += v * v;
    }
    __shared__ float ls[256], ls2[256];
    ls[threadIdx.x] = s;
    ls2[threadIdx.x] = s2;
    __syncthreads();
    if (threadIdx.x < F) {
#pragma unroll
        for (int g = 1; g < RG; ++g) { s += ls[g * F + f]; s2 += ls2[g * F + f]; }
        atomicAdd(&gsum[f], s);
        atomicAdd(&gsumsq[f], s2);
    }
}

__global__ void bn_final_k(const float* __restrict__ gsum,
                           const float* __restrict__ gsumsq,
                           const float* __restrict__ gamma,
                           const float* __restrict__ beta,
                           float* __restrict__ scale, float* __restrict__ shift,
                           int N, int F)
{
    int f = threadIdx.x;
    if (f >= F) return;
    float inv = 1.f / (float)N;
    float mu = gsum[f] * inv;
    float var = gsumsq[f] * inv - mu * mu;
    var = fmaxf(var, 0.f);
    float rs = rsqrtf(var + 1e-5f);
    float sc = rs * gamma[f];
    scale[f] = sc;
    shift[f] = beta[f] - mu * sc;
}

__global__ __launch_bounds__(256) void out_final_k(
    const float* __restrict__ x, const float* __restrict__ scale,
    const float* __restrict__ shift, float* __restrict__ out, int total)
{
    int i = blockIdx.x * 256 + threadIdx.x;
    if (i >= total) return;
    int f = i & 31;
    out[i] = fmaxf(x[i] * scale[f] + shift[f], 0.f);
}

// ---------------------------------------------------------------------------

extern "C" void kernel_launch(void* const* d_in, const int* in_sizes, int n_in,
                              void* d_out, int out_size, void* d_ws,
                              size_t ws_size, hipStream_t stream)
{
    const float* x   = (const float*)d_in[0];
    const float* W1  = (const float*)d_in[1];
    const float* as1 = (const float*)d_in[2];
    const float* ad1 = (const float*)d_in[3];
    const float* g1  = (const float*)d_in[5];
    const float* be1 = (const float*)d_in[6];
    const float* W2  = (const float*)d_in[7];
    const float* as2 = (const float*)d_in[8];
    const float* ad2 = (const float*)d_in[9];
    const float* g2  = (const float*)d_in[11];
    const float* be2 = (const float*)d_in[12];
    const float* W3  = (const float*)d_in[13];
    const float* as3 = (const float*)d_in[14];
    const float* ad3 = (const float*)d_in[15];
    const float* g3  = (const float*)d_in[17];
    const float* be3 = (const float*)d_in[18];
    const int*   ei  = (const int*)d_in[19];

    const int N  = in_sizes[0] / 128;   // 50000
    const int E  = in_sizes[19] / 2;    // 800000
    const int Et = E + N;
    const int nb = (N + 255) / 256;     // scan blocks (196 <= 256)

    // Workspace layout (4-byte words).
    float* ws = (float*)d_ws;
    size_t off = 0;
    float* Hb  = ws + off;  off += (size_t)N * 64;
    float* AGG = ws + off;  off += (size_t)N * 64;
    float* ES  = ws + off;  off += (size_t)N * 2;
    float* ED  = ws + off;  off += (size_t)N * 2;
    float* GS  = ws + off;  off += 64;
    float* GS2 = ws + off;  off += 64;
    float* SC  = ws + off;  off += 64;
    float* SH  = ws + off;  off += 64;
    int* deg    = (int*)(ws + off);  off += N;        // reused as scatter cursor
    int* rowtmp = (int*)(ws + off);  off += N;
    int* bsum   = (int*)(ws + off);  off += 256;
    int* boff   = (int*)(ws + off);  off += 256;
    int* rowptr = (int*)(ws + off);  off += (size_t)N + 1;
    int* col    = (int*)(ws + off);  off += (size_t)Et;

    const int gemmBlocks64 = (((N + 7) / 8) * 64 + 255) / 256;
    const int gemmBlocks32 = (((N + 7) / 8) * 32 + 255) / 256;
    const int attnBlocks64 = (N * 64 + 255) / 256;
    const int attnBlocks32 = (N * 32 + 255) / 256;
    const int edgeBlocks   = (Et + 255) / 256;
    const int aggBlocks64  = (int)(((size_t)N * 64 + 255) / 256);
    const int aggBlocks32  = (int)(((size_t)N * 32 + 255) / 256);

    // ---------------- CSR build (once per call) ----------------
    hipMemsetAsync(deg, 0, (size_t)N * sizeof(int), stream);
    deg_k<<<edgeBlocks, 256, 0, stream>>>(ei, deg, E, N);
    scan1_k<<<nb, 256, 0, stream>>>(deg, rowtmp, bsum, N);
    scan2_k<<<1, 256, 0, stream>>>(bsum, boff, nb);
    scan3_k<<<nb, 256, 0, stream>>>(rowtmp, boff, rowptr, N, Et);
    hipMemsetAsync(deg, 0, (size_t)N * sizeof(int), stream);   // now cursor
    scatter_k<<<edgeBlocks, 256, 0, stream>>>(ei, rowptr, deg, col, E, N);

    // ---------------- Layer 1: 128 -> [2 x 32] ----------------
    gemm_k<128, 64, false><<<gemmBlocks64, 256, 0, stream>>>(x, W1, nullptr, nullptr, Hb, N);
    attn_k<64, 2><<<attnBlocks64, 256, 0, stream>>>(Hb, as1, ad1, ES, ED, N);
    node_agg_k<2><<<aggBlocks64, 256, 0, stream>>>(rowptr, col, ES, ED, Hb, AGG, N);
    hipMemsetAsync(GS, 0, 128 * sizeof(float), stream);
    bn_stats_k<64><<<256, 256, 0, stream>>>(AGG, GS, GS2, N);
    bn_final_k<<<1, 64, 0, stream>>>(GS, GS2, g1, be1, SC, SH, N, 64);

    // ---------------- Layer 2: 64 -> [2 x 32] ----------------
    gemm_k<64, 64, true><<<gemmBlocks64, 256, 0, stream>>>(AGG, W2, SC, SH, Hb, N);
    attn_k<64, 2><<<attnBlocks64, 256, 0, stream>>>(Hb, as2, ad2, ES, ED, N);
    node_agg_k<2><<<aggBlocks64, 256, 0, stream>>>(rowptr, col, ES, ED, Hb, AGG, N);
    hipMemsetAsync(GS, 0, 128 * sizeof(float), stream);
    bn_stats_k<64><<<256, 256, 0, stream>>>(AGG, GS, GS2, N);
    bn_final_k<<<1, 64, 0, stream>>>(GS, GS2, g2, be2, SC, SH, N, 64);

    // ---------------- Layer 3: 64 -> [1 x 32] ----------------
    gemm_k<64, 32, true><<<gemmBlocks32, 256, 0, stream>>>(AGG, W3, SC, SH, Hb, N);
    attn_k<32, 1><<<attnBlocks32, 256, 0, stream>>>(Hb, as3, ad3, ES, ED, N);
    node_agg_k<1><<<aggBlocks32, 256, 0, stream>>>(rowptr, col, ES, ED, Hb, AGG, N);
    hipMemsetAsync(GS, 0, 128 * sizeof(float), stream);
    bn_stats_k<32><<<256, 256, 0, stream>>>(AGG, GS, GS2, N);
    bn_final_k<<<1, 32, 0, stream>>>(GS, GS2, g3, be3, SC, SH, N, 32);
    out_final_k<<<attnBlocks32, 256, 0, stream>>>(AGG, SC, SH, (float*)d_out, N * 32);
}